// Round 3
// baseline (587.771 us; speedup 1.0000x reference)
//
#include <hip/hip_runtime.h>

#define M_TOK 8192
#define N_OUT 4096
#define K_DIM 4096
#define NGROUPS 32          // K/128

typedef __bf16 bf16x8 __attribute__((ext_vector_type(8)));
typedef __bf16 bf16x4 __attribute__((ext_vector_type(4)));
typedef float  f32x4  __attribute__((ext_vector_type(4)));

#define GLOBAL_CVP const __attribute__((address_space(1))) void*
#define LDS_VP __attribute__((address_space(3))) void*

// ---------------- fused prep: x fp32->bf16  +  wq dequant->bf16 ----------------
// blocks [0, 4096): convert x. 4096*256 threads * 4 chunks = 4,194,304 chunks of 8.
// blocks [4096, 6144): dequant w. 2048*256 threads * 4 chunks = 2,097,152 chunks of 8.
#define XBLOCKS 4096
#define WBLOCKS 2048
__global__ __launch_bounds__(256)
void prep_kernel(const float* __restrict__ x,
                 const int* __restrict__ wq,
                 const float* __restrict__ scales,
                 const float* __restrict__ zeros,
                 __bf16* __restrict__ xb,
                 __bf16* __restrict__ wb)
{
    const int bid = blockIdx.x;
    if (bid < XBLOCKS) {
        const size_t T = (size_t)XBLOCKS * 256;
        const size_t base = (size_t)bid * 256 + threadIdx.x;
        float4 v[8];
#pragma unroll
        for (int t = 0; t < 4; t++) {
            const size_t i = base + (size_t)t * T;
            v[2 * t]     = ((const float4*)x)[2 * i];
            v[2 * t + 1] = ((const float4*)x)[2 * i + 1];
        }
#pragma unroll
        for (int t = 0; t < 4; t++) {
            const size_t i = base + (size_t)t * T;
            bf16x8 b;
            b[0] = (__bf16)v[2*t].x;   b[1] = (__bf16)v[2*t].y;
            b[2] = (__bf16)v[2*t].z;   b[3] = (__bf16)v[2*t].w;
            b[4] = (__bf16)v[2*t+1].x; b[5] = (__bf16)v[2*t+1].y;
            b[6] = (__bf16)v[2*t+1].z; b[7] = (__bf16)v[2*t+1].w;
            ((bf16x8*)xb)[i] = b;
        }
    } else {
        const size_t T = (size_t)WBLOCKS * 256;
        const size_t base = (size_t)(bid - XBLOCKS) * 256 + threadIdx.x;
        int4 q[8];
        float s[4], z[4];
#pragma unroll
        for (int t = 0; t < 4; t++) {
            const size_t i = base + (size_t)t * T;
            q[2 * t]     = ((const int4*)wq)[2 * i];
            q[2 * t + 1] = ((const int4*)wq)[2 * i + 1];
            const size_t e = i * 8;
            const int row = (int)(e >> 12);        // / K_DIM
            const int g   = ((int)e & 4095) >> 7;  // group (8 | 128, no straddle)
            s[t] = scales[row * NGROUPS + g];
            z[t] = zeros [row * NGROUPS + g];
        }
#pragma unroll
        for (int t = 0; t < 4; t++) {
            const size_t i = base + (size_t)t * T;
            bf16x8 b;
            b[0] = (__bf16)fmaf((float)q[2*t].x,   s[t], z[t]);
            b[1] = (__bf16)fmaf((float)q[2*t].y,   s[t], z[t]);
            b[2] = (__bf16)fmaf((float)q[2*t].z,   s[t], z[t]);
            b[3] = (__bf16)fmaf((float)q[2*t].w,   s[t], z[t]);
            b[4] = (__bf16)fmaf((float)q[2*t+1].x, s[t], z[t]);
            b[5] = (__bf16)fmaf((float)q[2*t+1].y, s[t], z[t]);
            b[6] = (__bf16)fmaf((float)q[2*t+1].z, s[t], z[t]);
            b[7] = (__bf16)fmaf((float)q[2*t+1].w, s[t], z[t]);
            ((bf16x8*)wb)[i] = b;
        }
    }
}

// ---------------- main: bf16 GEMM, B^T input, m97 structure (UNCHANGED) ------
__global__ __launch_bounds__(256)
void gemm_bt_kernel(const __bf16* __restrict__ A, const __bf16* __restrict__ B,
                    const float* __restrict__ bias, float* __restrict__ out) {
    __shared__ __bf16 As[128 * 32];   // 8 KB, unpadded (global_load_lds layout rule)
    __shared__ __bf16 Bs[128 * 32];   // 8 KB

    const int tid  = threadIdx.x;
    const int wave = tid >> 6;
    const int lane = tid & 63;
    const int m0 = blockIdx.x * 128;
    const int n0 = blockIdx.y * 128;
    const int wm = (wave & 1) * 64;
    const int wn = (wave >> 1) * 64;
    const int lrow = lane & 15;
    const int quad = lane >> 4;

    const int sbase = wave * 32;
    const int lr = lane >> 2;          // row within 16-row chunk
    const int lc = (lane & 3) * 8;     // element col within BK=32

    const __bf16* ap0 = A + (size_t)(m0 + sbase + lr) * K_DIM + lc;
    const __bf16* ap1 = ap0 + (size_t)16 * K_DIM;
    const __bf16* bp0 = B + (size_t)(n0 + sbase + lr) * K_DIM + lc;
    const __bf16* bp1 = bp0 + (size_t)16 * K_DIM;

    __bf16* la0 = &As[sbase * 32];
    __bf16* la1 = &As[(sbase + 16) * 32];
    __bf16* lb0 = &Bs[sbase * 32];
    __bf16* lb1 = &Bs[(sbase + 16) * 32];

    f32x4 acc[4][4];
#pragma unroll
    for (int i = 0; i < 4; i++)
#pragma unroll
        for (int j = 0; j < 4; j++)
            acc[i][j] = (f32x4){0.f, 0.f, 0.f, 0.f};

    for (int k0 = 0; k0 < K_DIM; k0 += 32) {
        __builtin_amdgcn_global_load_lds((GLOBAL_CVP)(ap0 + k0), (LDS_VP)la0, 16, 0, 0);
        __builtin_amdgcn_global_load_lds((GLOBAL_CVP)(ap1 + k0), (LDS_VP)la1, 16, 0, 0);
        __builtin_amdgcn_global_load_lds((GLOBAL_CVP)(bp0 + k0), (LDS_VP)lb0, 16, 0, 0);
        __builtin_amdgcn_global_load_lds((GLOBAL_CVP)(bp1 + k0), (LDS_VP)lb1, 16, 0, 0);
        __syncthreads();

        bf16x8 af[4], bfr[4];
#pragma unroll
        for (int i = 0; i < 4; i++) {
            af[i]  = *(const bf16x8*)&As[(wm + i * 16 + lrow) * 32 + quad * 8];
            bfr[i] = *(const bf16x8*)&Bs[(wn + i * 16 + lrow) * 32 + quad * 8];
        }

#pragma unroll
        for (int i = 0; i < 4; i++)
#pragma unroll
            for (int j = 0; j < 4; j++)
                acc[i][j] = __builtin_amdgcn_mfma_f32_16x16x32_bf16(af[i], bfr[j], acc[i][j], 0, 0, 0);

        __syncthreads();
    }

    // epilogue: D row=(lane>>4)*4+reg, col=lane&15 ; add bias
#pragma unroll
    for (int j = 0; j < 4; j++) {
        const int col = n0 + wn + j * 16 + lrow;
        const float bv = bias[col];
#pragma unroll
        for (int i = 0; i < 4; i++) {
            const int rowb = m0 + wm + i * 16 + quad * 4;
#pragma unroll
            for (int r = 0; r < 4; r++)
                out[(size_t)(rowb + r) * N_OUT + col] = acc[i][j][r] + bv;
        }
    }
}

// ---------------- fallback (round-1 fused kernel, used if ws too small) ----
#define LDS_STRIDE 40
__global__ __launch_bounds__(256)
void qlinear_fused_kernel(const float* __restrict__ x,
                          const int*   __restrict__ wq,
                          const float* __restrict__ scales,
                          const float* __restrict__ zeros,
                          const float* __restrict__ bias,
                          float*       __restrict__ out)
{
    __shared__ __bf16 As[128 * LDS_STRIDE];
    __shared__ __bf16 Bs[128 * LDS_STRIDE];
    const int tid  = threadIdx.x;
    const int m0   = blockIdx.x * 128;
    const int n0   = blockIdx.y * 128;
    const int wave = tid >> 6;
    const int lane = tid & 63;
    const int wm   = (wave & 1) * 64;
    const int wn   = (wave >> 1) * 64;
    const int lrow = lane & 15;
    const int quad = lane >> 4;
    const int srow = tid >> 3;
    const int scol = (tid & 7) * 4;

    f32x4 acc[4][4];
#pragma unroll
    for (int i = 0; i < 4; i++)
#pragma unroll
        for (int j = 0; j < 4; j++)
            acc[i][j] = (f32x4){0.f, 0.f, 0.f, 0.f};

    for (int k0 = 0; k0 < K_DIM; k0 += 32) {
        const int g = k0 >> 7;
#pragma unroll
        for (int rr = 0; rr < 4; rr++) {
            const int row = srow + rr * 32;
            const float4 v = *(const float4*)(x + (size_t)(m0 + row) * K_DIM + k0 + scol);
            bf16x4 b;
            b[0] = (__bf16)v.x; b[1] = (__bf16)v.y;
            b[2] = (__bf16)v.z; b[3] = (__bf16)v.w;
            *(bf16x4*)&As[row * LDS_STRIDE + scol] = b;
        }
#pragma unroll
        for (int rr = 0; rr < 4; rr++) {
            const int row = srow + rr * 32;
            const int4 q = *(const int4*)(wq + (size_t)(n0 + row) * K_DIM + k0 + scol);
            const float s = scales[(n0 + row) * NGROUPS + g];
            const float z = zeros [(n0 + row) * NGROUPS + g];
            bf16x4 b;
            b[0] = (__bf16)fmaf((float)q.x, s, z);
            b[1] = (__bf16)fmaf((float)q.y, s, z);
            b[2] = (__bf16)fmaf((float)q.z, s, z);
            b[3] = (__bf16)fmaf((float)q.w, s, z);
            *(bf16x4*)&Bs[row * LDS_STRIDE + scol] = b;
        }
        __syncthreads();
        bf16x8 af[4], bfr[4];
#pragma unroll
        for (int i = 0; i < 4; i++) {
            af[i]  = *(const bf16x8*)&As[(wm + i * 16 + lrow) * LDS_STRIDE + quad * 8];
            bfr[i] = *(const bf16x8*)&Bs[(wn + i * 16 + lrow) * LDS_STRIDE + quad * 8];
        }
#pragma unroll
        for (int i = 0; i < 4; i++)
#pragma unroll
            for (int j = 0; j < 4; j++)
                acc[i][j] = __builtin_amdgcn_mfma_f32_16x16x32_bf16(af[i], bfr[j], acc[i][j], 0, 0, 0);
        __syncthreads();
    }
#pragma unroll
    for (int j = 0; j < 4; j++) {
        const int col = n0 + wn + j * 16 + lrow;
        const float bv = bias[col];
#pragma unroll
        for (int i = 0; i < 4; i++) {
            const int rowb = m0 + wm + i * 16 + quad * 4;
#pragma unroll
            for (int r = 0; r < 4; r++)
                out[(size_t)(rowb + r) * N_OUT + col] = acc[i][j][r] + bv;
        }
    }
}

extern "C" void kernel_launch(void* const* d_in, const int* in_sizes, int n_in,
                              void* d_out, int out_size, void* d_ws, size_t ws_size,
                              hipStream_t stream) {
    const float* x      = (const float*)d_in[0];
    const int*   wq     = (const int*)  d_in[1];
    const float* scales = (const float*)d_in[2];
    const float* zeros  = (const float*)d_in[3];
    const float* bias   = (const float*)d_in[4];
    float*       out    = (float*)d_out;

    const size_t xb_bytes = (size_t)M_TOK * K_DIM * 2;   // 67.1 MB
    const size_t wb_bytes = (size_t)N_OUT * K_DIM * 2;   // 33.6 MB

    if (ws_size >= xb_bytes + wb_bytes) {
        __bf16* xb = (__bf16*)d_ws;
        __bf16* wb = (__bf16*)((char*)d_ws + xb_bytes);
        prep_kernel<<<XBLOCKS + WBLOCKS, 256, 0, stream>>>(x, wq, scales, zeros, xb, wb);
        dim3 grid(M_TOK / 128, N_OUT / 128);
        gemm_bt_kernel<<<grid, 256, 0, stream>>>(xb, wb, bias, out);
    } else {
        dim3 grid(M_TOK / 128, N_OUT / 128);
        qlinear_fused_kernel<<<grid, 256, 0, stream>>>(x, wq, scales, zeros, bias, out);
    }
}